// Round 8
// baseline (291.956 us; speedup 1.0000x reference)
//
#include <hip/hip_runtime.h>
#include <hip/hip_bf16.h>

typedef unsigned short u16;
typedef __attribute__((ext_vector_type(8))) short short8;
typedef __attribute__((ext_vector_type(4))) short short4v;
typedef __attribute__((ext_vector_type(4))) float f32x4;
typedef __attribute__((ext_vector_type(4))) float float4v;
typedef __attribute__((ext_vector_type(2))) float f32x2;

#define DMODEL 1024
#define DI 2048
#define NST 16
#define RANK 64
#define BB 2
#define LL 2048
#define MM (BB*LL)
#define LC 32
#define NCH (LL/LC)

__device__ __forceinline__ float b2f(u16 v){ union{unsigned u; float f;}x; x.u=(unsigned)v<<16; return x.f; }
__device__ __forceinline__ u16 f2b(float f){
  union{unsigned u; float f;}x; x.f=f;
  unsigned r = x.u + 0x7FFFu + ((x.u>>16)&1u);   // RNE
  return (u16)(r>>16);
}
// dtype probe on A_log: A_log[0]=log(1)=0.0f. f32 buffer -> u16[1]==0 (R5-validated: f32).
__device__ __forceinline__ bool probe_bf(const u16* probe){ return probe[1] != 0; }
__device__ __forceinline__ float ldin(const void* p, size_t i, bool bf){
  return bf ? b2f(((const u16*)p)[i]) : ((const float*)p)[i];
}
__device__ __forceinline__ u16 ldb(const void* p, size_t i, bool bf){
  return bf ? ((const u16*)p)[i] : f2b(((const float*)p)[i]);
}
// async global->LDS, 16B/lane; lds base MUST be wave-uniform (HW scatters lane*16)
__device__ __forceinline__ void gl16(const u16* g, char* lds_wave_base){
  __builtin_amdgcn_global_load_lds((const __attribute__((address_space(1))) unsigned*)g,
                                   (__attribute__((address_space(3))) unsigned*)lds_wave_base, 16, 0, 0);
}

// ============ 256x256 MFMA GEMM -- m201-style 8-phase schedule (T2+T3+T4+T5) ============
// (R7-verified: 43.9us GEMM1, MfmaUtil 30.7%, 0 conflicts.)  GEMM1 only now.
// BK=64, 512 thr = 8 waves. STRIPE layout: wave (wr,wc) owns rows {wr*16+s*32, s=0..7},
// cols {wc*16+s2*64, s2=0..3} -> each LDS half-tile (A0/A1/B0/B1, 16KB) is read entirely
// in ONE phase: P1=(A0,B0):12 ds_read, P2=(B1):4, P3=(A1):8, P4: 0.  One half-tile
// stage (2 gl16) per phase into a provably-idle region:
//   P1->A1(kt+1), P2->B1(kt+1), P3->A0(kt+2), P4->B0(kt+2).
// vmcnt(4) ONCE per K-tile at P4 -- never 0 mid-loop.  Per phase: reads; stage;
// barrier; lgkmcnt(0); sched_barrier (rule 18); setprio(1); 16 MFMA; setprio(0); barrier.
// Swizzle (rule 21, both sides): 16B-chunk ^= row&7 (0-conflict at 128B rows).
// EPI: 1 = f32 partial store; 4 = bf16 x/z split via LDS-staged coalesced stores.
template<int EPI>
__global__ __launch_bounds__(512,2) void mgemm256_k(
    const u16* __restrict__ A, const u16* __restrict__ Bt,
    void* __restrict__ O0, void* __restrict__ O1,
    int M, int N, int K, int lda, int ldb, int ldc)
{
  __shared__ char smem[131072];
  const int t = threadIdx.x;
  int bx = blockIdx.x, by = blockIdx.y;
  { // XCD swizzle (bijective since gridX*gridY % 8 == 0)
    const int gx = gridDim.x;
    const int nwg = gx*gridDim.y;
    const int lin = by*gx + bx;
    const int swz = (lin & 7)*(nwg>>3) + (lin>>3);
    bx = swz % gx; by = swz / gx;
  }
  const int m0 = by*256, n0 = bx*256;
  const int kbeg = blockIdx.z * K;
  const int wv = t >> 6, ln = t & 63;
  const int wr = wv >> 2, wc = wv & 3;
  const int lr = ln & 15, q = ln >> 4;
  const int NT = K >> 6;

  // ---- staging geometry: one half-tile = 128 rows x 64k = 16KB = 2 gl16/thread
  const int srow8 = ln >> 3;                       // 0..7
  const int koff = ((ln & 7) ^ srow8) * 8;         // pre-XOR'd source chunk (u16 off)
  auto stA = [&](int kt, int h){
    char* d = smem + (kt&1)*65536 + h*16384;
    const u16* g = A + (size_t)(m0 + h*128 + wv*8 + srow8)*lda + kbeg + kt*64 + koff;
    gl16(g, d + wv*1024);
    gl16(g + (size_t)64*lda, d + 8192 + wv*1024);
  };
  auto stB = [&](int kt, int h){
    char* d = smem + (kt&1)*65536 + 32768 + h*16384;
    const u16* g = Bt + (size_t)(n0 + h*128 + wv*8 + srow8)*ldb + kbeg + kt*64 + koff;
    gl16(g, d + wv*1024);
    gl16(g + (size_t)64*ldb, d + 8192 + wv*1024);
  };

  // ---- ds_read offsets: stripe s rows wr*16+s*32 (half s>>2); stripe s2 cols wc*16+s2*64
  int arow[8], brow[4], ck[2];
#pragma unroll
  for(int s=0;s<8;s++)  arow[s] = (s>>2)*16384 + (wr*16 + (s&3)*32 + lr)*128;
#pragma unroll
  for(int s2=0;s2<4;s2++) brow[s2] = 32768 + (s2>>1)*16384 + (wc*16 + (s2&1)*64 + lr)*128;
#pragma unroll
  for(int ks=0;ks<2;ks++) ck[ks] = ((ks*4 + q) ^ (lr & 7)) * 16;

  f32x4 acc[8][4];
#pragma unroll
  for(int i=0;i<8;i++)
#pragma unroll
    for(int j=0;j<4;j++) acc[i][j] = (f32x4){0.f,0.f,0.f,0.f};

  // ---- prologue: tile0 complete + A0,B0 of tile1 in flight (steady-state entry)
  stA(0,0); stB(0,0); stA(0,1); stB(0,1);
  stA(1,0); stB(1,0);
  asm volatile("s_waitcnt vmcnt(4)" ::: "memory");
  __builtin_amdgcn_sched_barrier(0);
  __builtin_amdgcn_s_barrier();
  __builtin_amdgcn_sched_barrier(0);

  short8 aR[4][2], b0R[2][2], b1R[2][2];
  for(int kt=0; kt<NT; ++kt){
    const char* base = smem + (kt&1)*65536;
    // ======== P1: reads A0 stripes + B0 stripes; stage A1(kt+1) ========
#pragma unroll
    for(int s=0;s<4;s++)
#pragma unroll
      for(int ks=0;ks<2;ks++) aR[s][ks] = *(const short8*)(base + arow[s] + ck[ks]);
#pragma unroll
    for(int j=0;j<2;j++)
#pragma unroll
      for(int ks=0;ks<2;ks++) b0R[j][ks] = *(const short8*)(base + brow[j] + ck[ks]);
    if(kt+1 < NT) stA(kt+1, 1);
    __builtin_amdgcn_s_barrier();
    asm volatile("s_waitcnt lgkmcnt(0)" ::: "memory");
    __builtin_amdgcn_sched_barrier(0);
    __builtin_amdgcn_s_setprio(1);
#pragma unroll
    for(int s=0;s<4;s++)
#pragma unroll
      for(int j=0;j<2;j++)
#pragma unroll
        for(int ks=0;ks<2;ks++)
          acc[s][j] = __builtin_amdgcn_mfma_f32_16x16x32_bf16(aR[s][ks], b0R[j][ks], acc[s][j], 0,0,0);
    __builtin_amdgcn_s_setprio(0);
    __builtin_amdgcn_s_barrier();
    __builtin_amdgcn_sched_barrier(0);
    // ======== P2: reads B1 stripes; stage B1(kt+1) ========
#pragma unroll
    for(int j=0;j<2;j++)
#pragma unroll
      for(int ks=0;ks<2;ks++) b1R[j][ks] = *(const short8*)(base + brow[2+j] + ck[ks]);
    if(kt+1 < NT) stB(kt+1, 1);
    __builtin_amdgcn_s_barrier();
    asm volatile("s_waitcnt lgkmcnt(0)" ::: "memory");
    __builtin_amdgcn_sched_barrier(0);
    __builtin_amdgcn_s_setprio(1);
#pragma unroll
    for(int s=0;s<4;s++)
#pragma unroll
      for(int j=0;j<2;j++)
#pragma unroll
        for(int ks=0;ks<2;ks++)
          acc[s][2+j] = __builtin_amdgcn_mfma_f32_16x16x32_bf16(aR[s][ks], b1R[j][ks], acc[s][2+j], 0,0,0);
    __builtin_amdgcn_s_setprio(0);
    __builtin_amdgcn_s_barrier();
    __builtin_amdgcn_sched_barrier(0);
    // ======== P3: reads A1 stripes; stage A0(kt+2) ========
#pragma unroll
    for(int s=0;s<4;s++)
#pragma unroll
      for(int ks=0;ks<2;ks++) aR[s][ks] = *(const short8*)(base + arow[4+s] + ck[ks]);
    if(kt+2 < NT) stA(kt+2, 0);
    __builtin_amdgcn_s_barrier();
    asm volatile("s_waitcnt lgkmcnt(0)" ::: "memory");
    __builtin_amdgcn_sched_barrier(0);
    __builtin_amdgcn_s_setprio(1);
#pragma unroll
    for(int s=0;s<4;s++)
#pragma unroll
      for(int j=0;j<2;j++)
#pragma unroll
        for(int ks=0;ks<2;ks++)
          acc[4+s][j] = __builtin_amdgcn_mfma_f32_16x16x32_bf16(aR[s][ks], b0R[j][ks], acc[4+s][j], 0,0,0);
    __builtin_amdgcn_s_setprio(0);
    __builtin_amdgcn_s_barrier();
    __builtin_amdgcn_sched_barrier(0);
    // ======== P4: no reads; stage B0(kt+2); per-tile counted vmcnt ========
    if(kt+2 < NT){
      stB(kt+2, 0);
      asm volatile("s_waitcnt vmcnt(4)" ::: "memory");   // tile kt+1 fully landed
    } else if(kt+1 < NT){
      asm volatile("s_waitcnt vmcnt(0)" ::: "memory");   // drain for final tile
    }
    __builtin_amdgcn_sched_barrier(0);
    __builtin_amdgcn_s_barrier();
    __builtin_amdgcn_sched_barrier(0);
    __builtin_amdgcn_s_setprio(1);
#pragma unroll
    for(int s=0;s<4;s++)
#pragma unroll
      for(int j=0;j<2;j++)
#pragma unroll
        for(int ks=0;ks<2;ks++)
          acc[4+s][2+j] = __builtin_amdgcn_mfma_f32_16x16x32_bf16(aR[s][ks], b1R[j][ks], acc[4+s][2+j], 0,0,0);
    __builtin_amdgcn_s_setprio(0);
    __builtin_amdgcn_s_barrier();
    __builtin_amdgcn_sched_barrier(0);
  }

  // C/D per 16x16 frag (s,s2): row = m0 + wr*16 + s*32 + q*4 + r; col = n0 + wc*16 + s2*64 + lr
  if(EPI==4){
    u16* tile = (u16*)smem;                // [128][264] u16, reused LDS
    u16* obase = (n0 < DI) ? (u16*)O0 : (u16*)O1;
    const int cb = n0 & (DI-1);
    for(int h=0;h<2;h++){                  // h=0: frags s=0..3 (rows 0..127); h=1: s=4..7
      __builtin_amdgcn_s_barrier();
#pragma unroll
      for(int s=0;s<4;s++)
#pragma unroll
        for(int r=0;r<4;r++){
          int trow = wr*16 + s*32 + q*4 + r;       // 0..127 within half
#pragma unroll
          for(int s2=0;s2<4;s2++)
            tile[trow*264 + wc*16 + s2*64 + lr] = f2b(acc[h*4+s][s2][r]);
        }
      asm volatile("s_waitcnt lgkmcnt(0)" ::: "memory");
      __builtin_amdgcn_sched_barrier(0);
      __builtin_amdgcn_s_barrier();
      __builtin_amdgcn_sched_barrier(0);
#pragma unroll
      for(int it=0;it<8;it++){
        int idx = it*512 + t;              // 0..4095
        int row = idx >> 5;                // 0..127
        int ch  = (idx & 31) * 8;          // 0..248
        short8 v = *(const short8*)(tile + row*264 + ch);
        *(short8*)(obase + (size_t)(m0 + h*128 + row)*ldc + cb + ch) = v;
      }
    }
    return;
  }
  // EPI==1: direct f32 partial stores (16-lane contiguous 64B segments)
#pragma unroll
  for(int s=0;s<8;s++){
#pragma unroll
    for(int r=0;r<4;r++){
      int row = m0 + wr*16 + s*32 + q*4 + r;
#pragma unroll
      for(int s2=0;s2<4;s2++){
        int col = n0 + wc*16 + s2*64 + lr;
        ((float*)O0)[(size_t)blockIdx.z*M*ldc + (size_t)row*ldc + col] = acc[s][s2][r];
      }
    }
  }
}

// ---------------- MFMA GEMM 128x128 (m97 structure) -- GEMM3 (EPI1) + GEMM7 (EPI2) ------
// EPI1: f32 partial store to O0 + z*M*ldc (split-K).
// EPI2: direct flagged FINAL store (f32/bf16 per probe) -- GEMM7 single-pass, no red7:
//       grid (N/128, M/128) = 256 blocks at K=2048 kills 134 MB of partial traffic.
template<int EPI>
__global__ __launch_bounds__(256,2) void mgemm_k(
    const u16* __restrict__ A, const u16* __restrict__ Bt,
    void* __restrict__ O0, void* __restrict__ O1,
    const void* __restrict__ bias, const u16* __restrict__ probe,
    int M, int N, int K, int lda, int ldb, int ldc)
{
  __shared__ char smem[16384];
  const int t = threadIdx.x;
  int bx = blockIdx.x, by = blockIdx.y;
  { // XCD swizzle (bijective since nwg%8==0)
    const int gx = gridDim.x;
    const int nwg = gx*gridDim.y;
    const int lin = by*gx + bx;
    const int swz = (lin & 7)*(nwg>>3) + (lin>>3);
    bx = swz % gx; by = swz / gx;
  }
  const int m0 = by*128, n0 = bx*128;
  const int kbeg = blockIdx.z * K;
  const int lane = t & 63;
  const int wv = t >> 6;
  const int wm = (wv>>1)*64, wn = (wv&1)*64;
  const int lr = lane & 15, q = lane >> 4;

  const int r0 = t>>2, q0 = t&3;
  const u16* Ag0 = A + kbeg + (size_t)(m0 + r0)*lda + q0*8;
  const u16* Ag1 = A + kbeg + (size_t)(m0 + 64 + r0)*lda + q0*8;
  const u16* Bg0 = Bt + kbeg + (size_t)(n0 + r0)*ldb + q0*8;
  const u16* Bg1 = Bt + kbeg + (size_t)(n0 + 64 + r0)*ldb + q0*8;
  char* const wbase = smem + (t & ~63)*16;
  char* const lA0 = wbase;
  char* const lA1 = wbase + 4096;
  char* const lB0 = wbase + 8192;
  char* const lB1 = wbase + 12288;

  int aro[4], bro[4];
#pragma unroll
  for(int i=0;i<4;i++) aro[i] = (wm + i*16 + lr)*64 + q*16;
#pragma unroll
  for(int j=0;j<4;j++) bro[j] = (wn + j*16 + lr)*64 + q*16;

  f32x4 acc[4][4];
#pragma unroll
  for(int i=0;i<4;i++)
#pragma unroll
    for(int j=0;j<4;j++) acc[i][j] = (f32x4){0.f,0.f,0.f,0.f};

  for(int k0=0;k0<K;k0+=32){
    __syncthreads();
    gl16(Ag0 + k0, lA0); gl16(Ag1 + k0, lA1);
    gl16(Bg0 + k0, lB0); gl16(Bg1 + k0, lB1);
    __syncthreads();
    short8 af[4], bfv[4];
#pragma unroll
    for(int i=0;i<4;i++) af[i] = *(const short8*)(smem + aro[i]);
#pragma unroll
    for(int j=0;j<4;j++) bfv[j] = *(const short8*)(smem + 8192 + bro[j]);
#pragma unroll
    for(int i=0;i<4;i++)
#pragma unroll
      for(int j=0;j<4;j++)
        acc[i][j] = __builtin_amdgcn_mfma_f32_16x16x32_bf16(af[i], bfv[j], acc[i][j], 0,0,0);
  }

  if(EPI==2){
    const bool bf = probe_bf(probe);
#pragma unroll
    for(int i=0;i<4;i++){
#pragma unroll
      for(int r=0;r<4;r++){
        int row = m0 + wm + i*16 + q*4 + r;
#pragma unroll
        for(int j=0;j<4;j++){
          int col = n0 + wn + j*16 + lr;
          float v = acc[i][j][r];
          if(bf) ((u16*)O0)[(size_t)row*ldc + col] = f2b(v);
          else   ((float*)O0)[(size_t)row*ldc + col] = v;
        }
      }
    }
    return;
  }
#pragma unroll
  for(int i=0;i<4;i++){
#pragma unroll
    for(int r=0;r<4;r++){
      int row = m0 + wm + i*16 + q*4 + r;
#pragma unroll
      for(int j=0;j<4;j++){
        int col = n0 + wn + j*16 + lr;
        ((float*)O0)[(size_t)blockIdx.z*M*ldc + (size_t)row*ldc + col] = acc[i][j][r];
      }
    }
  }
}

// ---------------- dt_k: delta = softplus(xdblb[:,:64] @ WdtT^T + b_dt) -> bf16 ----------------
// K=64 in ONE LDS shot: A 16KB + B 16KB, 8 gl16/thread, one barrier, 32 MFMA,
// branchless softplus, LDS-staged coalesced stores. (R5: fixed the 124us outlier.)
__global__ __launch_bounds__(256,2) void dt_k(
    const u16* __restrict__ A,      // xdblb [M][128], cols 0..63 used
    const u16* __restrict__ Bt,     // WdtT [2048][64]
    u16* __restrict__ O,            // dlb [M][2048]
    const void* __restrict__ bias, const u16* __restrict__ probe)
{
  const bool bf = probe_bf(probe);
  __shared__ char smem[33792];      // A @0 (16KB), B @16384 (16KB); epi reuses as [128][132] u16
  const int t = threadIdx.x;
  int bx = blockIdx.x, by = blockIdx.y;
  { // XCD swizzle (nwg = 512, %8==0)
    const int gx = gridDim.x;
    const int nwg = gx*gridDim.y;
    const int lin = by*gx + bx;
    const int swz = (lin & 7)*(nwg>>3) + (lin>>3);
    bx = swz % gx; by = swz / gx;
  }
  const int m0 = by*128, n0 = bx*128;
  const int lane = t & 63, wv = t >> 6;
  const int wm = (wv>>1)*64, wn = (wv&1)*64;
  const int lr = lane & 15, q = lane >> 4;

  // staging: 4 rounds x 32 rows; thread t -> row t>>3, 16B chunk t&7;
  // source k-chunk pre-XOR'd with row&7 (both-sides swizzle).
  const int srow = t >> 3;
  const int koff = (((t&7) ^ (srow&7)) * 8);       // u16 offset in 64-col row
  const u16* gA = A  + (size_t)(m0 + srow)*128 + koff;
  const u16* gB = Bt + (size_t)(n0 + srow)*64  + koff;
  char* const lA = smem + wv*1024;                 // wave-uniform; lane*16 covers 8 rows
  char* const lB = smem + 16384 + wv*1024;
#pragma unroll
  for(int r=0;r<4;r++){
    gl16(gA + (size_t)r*32*128, lA + r*4096);
    gl16(gB + (size_t)r*32*64,  lB + r*4096);
  }
  __syncthreads();                                 // full drain (vmcnt 0) + barrier

  f32x4 acc[4][4];
#pragma unroll
  for(int i=0;i<4;i++)
#pragma unroll
    for(int j=0;j<4;j++) acc[i][j] = (f32x4){0.f,0.f,0.f,0.f};

#pragma unroll
  for(int ks=0;ks<2;ks++){
    short8 af[4], bfv[4];
#pragma unroll
    for(int i=0;i<4;i++){
      int row = wm + i*16 + lr;
      af[i] = *(const short8*)(smem + row*128 + (((ks*4+q) ^ (row&7))*16));
    }
#pragma unroll
    for(int j=0;j<4;j++){
      int row = wn + j*16 + lr;
      bfv[j] = *(const short8*)(smem + 16384 + row*128 + (((ks*4+q) ^ (row&7))*16));
    }
#pragma unroll
    for(int i=0;i<4;i++)
#pragma unroll
      for(int j=0;j<4;j++)
        acc[i][j] = __builtin_amdgcn_mfma_f32_16x16x32_bf16(af[i], bfv[j], acc[i][j], 0,0,0);
  }

  // epilogue: bias + fast softplus -> LDS tile [128][132] -> coalesced short8 stores
  float bj[4];
#pragma unroll
  for(int j=0;j<4;j++) bj[j] = ldin(bias, n0 + wn + j*16 + lr, bf);
  __syncthreads();
  u16* tile = (u16*)smem;
#pragma unroll
  for(int i=0;i<4;i++)
#pragma unroll
    for(int r=0;r<4;r++){
      int trow = wm + i*16 + q*4 + r;
#pragma unroll
      for(int j=0;j<4;j++){
        int tcol = wn + j*16 + lr;
        float s = acc[i][j][r] + bj[j];
        float e = __expf(-fabsf(s));
        float sp = fmaxf(s, 0.f) + __logf(1.f + e);
        tile[trow*132 + tcol] = f2b(sp);
      }
    }
  __syncthreads();
#pragma unroll
  for(int it=0;it<8;it++){
    int idx = it*256 + t;            // 0..2047
    int row = idx >> 4;              // 0..127
    int colc = (idx & 15) * 8;       // 0..120
    short8 v = *(const short8*)(tile + row*132 + colc);
    *(short8*)(O + (size_t)(m0+row)*DI + n0 + colc) = v;
  }
}

// ---------------- prep: 4 weight transposes + hidden convert, one launch ----------------
__device__ __forceinline__ void tr_block(
    const void* src, u16* dst, int R, int C, int bx, int by, bool bf, bool perm,
    int tid, u16 (*tile)[33])
{
  const int c0 = bx*32, r0 = by*32;
  const int tc = tid & 31, tr0 = tid >> 5;
#pragma unroll
  for(int i=0;i<4;i++){
    int r = tr0 + i*8;
    int gc = c0 + tc;
    tile[r][tc] = (gc < C) ? ldb(src, (size_t)(r0+r)*C + gc, bf) : (u16)0;
  }
  __syncthreads();
#pragma unroll
  for(int i=0;i<4;i++){
    int dr = c0 + tr0 + i*8;
    if(perm) dr = (dr>>1) + ((dr&1)<<11);   // even cols -> rows 0..2047 (x), odd -> 2048..4095 (z)
    int dc = r0 + tc;
    dst[(size_t)dr*R + dc] = tile[tc][tr0 + i*8];
  }
}

__global__ __launch_bounds__(256) void prep_k(
    const void* __restrict__ W_in, const void* __restrict__ W_out,
    const void* __restrict__ W_x, const void* __restrict__ W_dt,
    const void* __restrict__ hidden,
    u16* __restrict__ WinT, u16* __restrict__ WoutT, u16* __restrict__ WxT,
    u16* __restrict__ WdtT, u16* __restrict__ hb, const u16* __restrict__ probe)
{
  const bool bf = probe_bf(probe);
  __shared__ u16 tile[32][33];
  const int bid = blockIdx.x, t = threadIdx.x;
  if(bid < 4096){                 // W_in [1024][4096] -> [4096][1024] permuted, grid 128x32
    tr_block(W_in, WinT, DMODEL, 2*DI, bid & 127, bid >> 7, bf, true, t, tile);
  } else if(bid < 6144){          // W_out [2048][1024] -> [1024][2048], grid 32x64
    int b2 = bid - 4096; tr_block(W_out, WoutT, DI, DMODEL, b2 & 31, b2 >> 5, bf, false, t, tile);
  } else if(bid < 6400){          // W_x [2048][96] -> [128][2048] pad, grid 4x64
    int b2 = bid - 6144; tr_block(W_x, WxT, DI, 96, b2 & 3, b2 >> 2, bf, false, t, tile);
  } else if(bid < 6528){          // W_dt [64][2048] -> [2048][64], grid 64x2
    int b2 = bid - 6400; tr_block(W_dt, WdtT, RANK, DI, b2 & 63, b2 >> 6, bf, false, t, tile);
  } else {                        // hidden convert -> bf16, 8 elems/thread
    size_t i = ((size_t)(bid - 6528)*256 + t)*8;
    if(bf){
      *(short8*)(hb+i) = *(const short8*)((const u16*)hidden + i);
    } else {
      float4v a = *(const float4v*)((const float*)hidden + i);
      float4v b = *(const float4v*)((const float*)hidden + i + 4);
      short8 r;
      r[0]=(short)f2b(a[0]); r[1]=(short)f2b(a[1]); r[2]=(short)f2b(a[2]); r[3]=(short)f2b(a[3]);
      r[4]=(short)f2b(b[0]); r[5]=(short)f2b(b[1]); r[6]=(short)f2b(b[2]); r[7]=(short)f2b(b[3]);
      *(short8*)(hb+i) = r;
    }
  }
}

// ---------------- split-K(8) reduce for xdbl: f32 + bf16 copies ----------------
__global__ __launch_bounds__(256) void redx_k(
    const float* __restrict__ P, float* __restrict__ xdbl, u16* __restrict__ xdblb)
{
  size_t i = ((size_t)blockIdx.x*256 + threadIdx.x)*4;   // over M*128
  float4v s = *(const float4v*)(P + i);
#pragma unroll
  for(int p=1;p<8;p++) s += *(const float4v*)(P + (size_t)p*MM*128 + i);
  *(float4v*)(xdbl + i) = s;
  short4v r; r[0]=(short)f2b(s[0]); r[1]=(short)f2b(s[1]); r[2]=(short)f2b(s[2]); r[3]=(short)f2b(s[3]);
  *(short4v*)(xdblb + i) = r;
}

// ---------------- depthwise conv (K=4, pad 1 left / 2 right) + bias + silu ----------------
__global__ __launch_bounds__(256) void conv_silu_k(
  const u16* __restrict__ xb, const void* __restrict__ w,
  const void* __restrict__ bias, u16* __restrict__ xcb,
  const u16* __restrict__ probe)
{
  const bool bf = probe_bf(probe);
  const int row = blockIdx.x;              // 0..MM-1
  const int tt = row & (LL-1);
  const int d = threadIdx.x*8;
  float wv[4][8], bv[8];
  if(bf){
    short8 bb = *(const short8*)((const u16*)bias + d);
#pragma unroll
    for(int j=0;j<8;j++) bv[j] = b2f((u16)bb[j]);
#pragma unroll
    for(int k=0;k<4;k++){
      short8 ww = *(const short8*)((const u16*)w + k*DI + d);
#pragma unroll
      for(int j=0;j<8;j++) wv[k][j] = b2f((u16)ww[j]);
    }
  } else {
    *(float4v*)(bv)   = *(const float4v*)((const float*)bias + d);
    *(float4v*)(bv+4) = *(const float4v*)((const float*)bias + d + 4);
#pragma unroll
    for(int k=0;k<4;k++){
      *(float4v*)(wv[k])   = *(const float4v*)((const float*)w + k*DI + d);
      *(float4v*)(wv[k]+4) = *(const float4v*)((const float*)w + k*DI + d + 4);
    }
  }
  float acc[8];
#pragma unroll
  for(int j=0;j<8;j++) acc[j] = bv[j];
  const u16* xrow = xb + (size_t)row*DI + d;
#pragma unroll
  for(int k=0;k<4;k++){
    int o = tt - 1 + k;
    if(0<=o && o<LL){
      short8 xv = *(const short8*)(xrow + (ptrdiff_t)(k-1)*DI);
#pragma unroll
      for(int j=0;j<8;j++) acc[j] = fmaf(b2f((u16)xv[j]), wv[k][j], acc[j]);
    }
  }
  short8 sb;
#pragma unroll
  for(int j=0;j<8;j++){ float s = acc[j] / (1.f + __expf(-acc[j])); sb[j]=(short)f2b(s); }
  *(short8*)(xcb + (size_t)row*DI + d) = sb;
}

// ---------------- chunked selective scan (1 channel/thread, LC=32) ----------------
// 1024 blocks = 4 waves/SIMD; inner loop unroll x2, prefetch depth 2.
__global__ __launch_bounds__(256,4) void scan_a_k(
  const u16* __restrict__ dlb, const u16* __restrict__ xcb,
  const float* __restrict__ xdbl, const void* __restrict__ A_log,
  float* __restrict__ Bacc, float* __restrict__ sumdv,
  const u16* __restrict__ probe)
{
  const bool bf = probe_bf(probe);
  __shared__ float Bsh[LC][NST];
  const int t = threadIdx.x;
  const int d0 = blockIdx.x*256 + t;
  const int b = blockIdx.y, c = blockIdx.z;
  for(int i=t;i<LC*NST;i+=256){
    int l = i>>4, n = i&15;
    Bsh[l][n] = xdbl[((size_t)b*LL + (size_t)c*LC + l)*128 + 64 + n];
  }
  __syncthreads();
  float ac[NST], s[NST];
#pragma unroll
  for(int n=0;n<NST;n++){
    ac[n] = -__expf(ldin(A_log, (size_t)d0*NST+n, bf));
    s[n]=0.f;
  }
  bool geom = true;
  {
    float a0 = ac[0];
#pragma unroll
    for(int n=1;n<NST;n++) geom = geom && (fabsf(ac[n]-(n+1)*a0) <= 1e-4f*(n+1)*fabsf(a0));
  }
  float sum=0.f;
  const size_t base0 = ((size_t)b*LL + (size_t)c*LC)*DI + d0;
  const u16* dptr = dlb + base0;
  const u16* xptr = xcb + base0;

  auto stepA = [&](int l, u16 dp, u16 xp){
    float dv=b2f(dp), xv=b2f(xp);
    float du=dv*xv;
    sum+=dv;
    if(geom){
      float e=__expf(ac[0]*dv);
      float p=1.f;
#pragma unroll
      for(int n=0;n<NST;n++){
        p*=e; s[n]=fmaf(p, s[n], du*Bsh[l][n]);
      }
    } else {
#pragma unroll
      for(int n=0;n<NST;n++)
        s[n]=fmaf(__expf(ac[n]*dv), s[n], du*Bsh[l][n]);
    }
  };

  u16 dpA = dptr[0], xpA = xptr[0];
  u16 dpB = dptr[DI], xpB = xptr[DI];
  for(int l=0;l<LC;l+=2){
    int l2 = (l+2 < LC) ? l+2 : LC-1;   // tail: harmless duplicate load
    int l3 = (l+3 < LC) ? l+3 : LC-1;
    u16 dpC = dptr[(size_t)l2*DI], xpC = xptr[(size_t)l2*DI];
    u16 dpD = dptr[(size_t)l3*DI], xpD = xptr[(size_t)l3*DI];
    stepA(l,   dpA, xpA);
    stepA(l+1, dpB, xpB);
    dpA=dpC; xpA=xpC; dpB=dpD; xpB=xpD;
  }

  const size_t ob = ((size_t)c*BB + b)*((size_t)NST*DI) + d0;
#pragma unroll
  for(int n=0;n<NST;n++) Bacc[ob + (size_t)n*DI] = s[n];
  sumdv[((size_t)c*BB + b)*DI + d0] = sum;
}

// Phase B: prefix over chunks; a-coef recomputed from sumdv (exact algebra).
__global__ __launch_bounds__(256) void scan_b_k(
  const float* __restrict__ Bacc, const float* __restrict__ sumdv,
  const void* __restrict__ A_log, float* __restrict__ Sin,
  const u16* __restrict__ probe)
{
  const bool bf = probe_bf(probe);
  const int idx = blockIdx.x*256 + threadIdx.x;   // b*(NST*DI)+n*DI+d
  const int d = idx & (DI-1);
  const int n = (idx >> 11) & 15;
  const int b = idx >> 15;
  const float ac = -__expf(ldin(A_log, (size_t)d*NST+n, bf));
  float s = 0.f;
  float svN = sumdv[((size_t)0*BB + b)*DI + d];
  float bbN = Bacc[idx];
  for(int c=0;c<NCH;c++){
    int c1 = (c+1 < NCH) ? c+1 : NCH-1;
    float svC = sumdv[((size_t)c1*BB + b)*DI + d];
    float bbC = Bacc[(size_t)c1*((size_t)BB*NST*DI) + idx];
    float a = __expf(ac * svN);
    Sin[(size_t)c*((size_t)BB*NST*DI) + idx] = s;
    s = fmaf(a, s, bbN);
    svN = svC; bbN = bbC;
  }
}

// Phase C fused with gate (1 channel/thread): G = (y + xc*D)*silu(z), bf16 out
__global__ __launch_bounds__(256,4) void scan_c_gate_k(
  const u16* __restrict__ dlb, const u16* __restrict__ xcb,
  const float* __restrict__ xdbl, const void* __restrict__ A_log,
  const float* __restrict__ Sin, const u16* __restrict__ zb,
  const void* __restrict__ Dw, u16* __restrict__ G,
  const u16* __restrict__ probe)
{
  const bool bf = probe_bf(probe);
  __shared__ float Bsh[LC][NST], Csh[LC][NST];
  const int t = threadIdx.x;
  const int d0 = blockIdx.x*256 + t;
  const int b = blockIdx.y, c = blockIdx.z;
  for(int i=t;i<LC*NST;i+=256){
    int l = i>>4, n = i&15;
    size_t ro = ((size_t)b*LL + (size_t)c*LC + l)*128;
    Bsh[l][n] = xdbl[ro + 64 + n];
    Csh[l][n] = xdbl[ro + 80 + n];
  }
  __syncthreads();
  float ac[NST], s[NST];
  const size_t ib = ((size_t)c*BB + b)*((size_t)NST*DI) + d0;
#pragma unroll
  for(int n=0;n<NST;n++)
    ac[n] = -__expf(ldin(A_log, (size_t)d0*NST+n, bf));
#pragma unroll
  for(int n=0;n<NST;n++) s[n] = Sin[ib + (size_t)n*DI];
  bool geom = true;
  {
    float a0 = ac[0];
#pragma unroll
    for(int n=1;n<NST;n++) geom = geom && (fabsf(ac[n]-(n+1)*a0) <= 1e-4f*(n+1)*fabsf(a0));
  }
  const float D0 = ldin(Dw, d0, bf);
  const size_t base0 = ((size_t)b*LL + (size_t)c*LC)*DI + d0;
  const u16* dptr = dlb + base0;
  const u16* xptr = xcb + base0;
  const u16* zptr = zb  + base0;

  auto stepC = [&](int l, u16 dp, u16 xp, u16 zz){
    float dv=b2f(dp), xv=b2f(xp);
    float du=dv*xv;
    float y=0.f;
    if(geom){
      float e=__expf(ac[0]*dv);
      float p=1.f;
#pragma unroll
      for(int n=0;n<NST;n++){
        p*=e; s[n]=fmaf(p, s[n], du*Bsh[l][n]); y=fmaf(s[n], Csh[l][n], y);
      }
    } else {
#pragma unroll
      for(int n=0;n<NST;n++){
        s[n]=fmaf(__expf(ac[n]*dv), s[n], du*Bsh[l][n]); y=fmaf(s[n], Csh[l][n], y);
      }
    }
    float z0 = b2f(zz);
    float g0 = z0 / (1.f + __expf(-z0));
    float o0 = (y + xv*D0) * g0;
    G[base0 + (size_t)l*DI] = f2b(o0);
  };

  u16 dpA = dptr[0], xpA = xptr[0], zzA = zptr[0];
  u16 dpB = dptr[DI], xpB = xptr[DI], zzB = zptr[DI];
  for(int l=0;l<LC;l+=2){
    int l2 = (l+2 < LC) ? l+2 : LC-1;
    int l3 = (l+3 < LC) ? l+3 : LC-1;
    u16 dpC = dptr[(size_t)l2*DI], xpC = xptr[(size_t)l2*DI], zzC = zptr[(size_t)l2*DI];
    u16 dpD = dptr[(size_t)l3*DI], xpD = xptr[(size_t)l3*DI], zzD = zptr[(size_t)l3*DI];
    stepC(l,   dpA, xpA, zzA);
    stepC(l+1, dpB, xpB, zzB);
    dpA=dpC; xpA=xpC; zzA=zzC; dpB=dpD; xpB=xpD; zzB=zzD;
  }
}

extern "C" void kernel_launch(void* const* d_in, const int* in_sizes, int n_in,
                              void* d_out, int out_size, void* d_ws, size_t ws_size,
                              hipStream_t stream)
{
  const void* hidden = d_in[0];
  const void* W_in   = d_in[1];
  const void* convw  = d_in[2];
  const void* convb  = d_in[3];
  const void* W_x    = d_in[4];
  const void* W_dt   = d_in[5];
  const void* b_dt   = d_in[6];
  const u16*  A_log  = (const u16*)d_in[7];   // also the dtype probe
  const void* Dw     = d_in[8];
  const void* W_out  = d_in[9];

  char* p = (char*)d_ws;
  u16*   xb   = (u16*)  p;                       // 16.8 MB (GEMM1 -> conv); then:
  float* Sin  = (float*)p;                       //   alias 16.8 MB (scan_b -> scan_c)
  u16*   zb   = (u16*)  (p + 16777216);          // 16.8 MB (GEMM1 -> scan_c)
  u16*   xcb  = (u16*)  (p + 33554432);          // 16.8 MB (conv -> GEMM3/scans)
  float* Bcc  = (float*)(p + 67108864);          // 16.8 MB (scan_a -> scan_b)
  u16*   G    = (u16*)  (p + 83886080);          // 16.8 MB (scan_c -> GEMM7)
  // 33.5 MB region at 100663296, sequential reuse:
  float* Pw   = (float*)(p + 100663296);         //   GEMM3 partials 8x2.1 MB (-> redx)
  u16*   dlb  = (u16*)  (p + 100663296);         //   delta bf16 16.8 MB (dt_k -> scans)
  u16*   hb   = (u16*)  (p + 117440512);         //   hidden bf16 8.4 MB (prep -> GEMM1)
  float* sumdv= (float*)(p + 117440512);         //   1 MB (scan_a -> scan_b; hb dead)
  float* xdbl = (float*)(p + 134217728);         // 2.1 MB  [M][128] f32
  u16*   xdblb= (u16*)  (p + 136314880);         // 1.05 MB [M][128] bf16
  u16*   WinT = (u16*)  (p + 137363456);         // 8.4 MB  [4096][1024] (row-permuted: x|z)
  u16*   WoutT= (u16*)  (p + 145752064);         // 4.2 MB  [1024][2048]
  u16*   WxT  = (u16*)  (p + 149946368);         // 0.5 MB  [128][2048] zero-padded
  u16*   WdtT = (u16*)  (p + 150470656);         // 0.25 MB [2048][64]

  // 0. one-shot prep: 4 transposes (W_in row-permuted) + hidden convert
  prep_k<<<6528 + (MM*DMODEL)/(256*8), 256, 0, stream>>>(
      W_in, W_out, W_x, W_dt, hidden, WinT, WoutT, WxT, WdtT, hb, A_log);
  // 1. xz = hidden @ W_in -> xb / zb, 256^2 8-phase pipelined GEMM
  mgemm256_k<4><<<dim3(16,16), 512, 0, stream>>>(hb, WinT, xb, zb,
                                                 MM, 2*DI, DMODEL, DMODEL, DMODEL, DI);
  // 2. xcb = silu(conv(xb)+bias)  (bf16 in/out, one block per row)
  conv_silu_k<<<MM, 256, 0, stream>>>(xb, convw, convb, xcb, A_log);
  // 3. xdbl = xc @ W_x  (N pad 128), split-K x8 -> partials -> reduce
  mgemm_k<1><<<dim3(1,32,8), 256, 0, stream>>>(xcb, WxT, Pw, nullptr, nullptr, A_log,
                                               MM, 128, DI/8, DI, DI, 128);
  redx_k<<<(MM*128)/(256*4), 256, 0, stream>>>(Pw, xdbl, xdblb);
  // 4. delta = softplus(xdbl[:, :64] @ W_dt + b_dt) -- dedicated single-shot kernel
  dt_k<<<dim3(16,32), 256, 0, stream>>>(xdblb, WdtT, dlb, b_dt, A_log);
  // 5. chunked selective scan (+ fused gate); 1 channel/thread, 1024 blocks
  scan_a_k<<<dim3(DI/256, BB, NCH), 256, 0, stream>>>(dlb, xcb, xdbl, A_log, Bcc, sumdv, A_log);
  scan_b_k<<<(BB*NST*DI)/256, 256, 0, stream>>>(Bcc, sumdv, A_log, Sin, A_log);
  scan_c_gate_k<<<dim3(DI/256, BB, NCH), 256, 0, stream>>>(dlb, xcb, xdbl, A_log, Sin, zb, Dw, G, A_log);
  // 6. out = G @ W_out -- SINGLE-PASS 128^2 (8x32 = 256 blocks, K=2048, no split-K):
  //    kills 67 MB partial write + 67 MB red7 read + red7 launch (~21 us of HBM).
  mgemm_k<2><<<dim3(DMODEL/128, MM/128), 256, 0, stream>>>(G, WoutT, d_out, nullptr, nullptr, A_log,
                                                           MM, DMODEL, DI, DI, DI, DMODEL);
}

// Round 9
// 285.264 us; speedup vs baseline: 1.0235x; 1.0235x over previous
//
#include <hip/hip_runtime.h>
#include <hip/hip_bf16.h>

typedef unsigned short u16;
typedef __attribute__((ext_vector_type(8))) short short8;
typedef __attribute__((ext_vector_type(4))) short short4v;
typedef __attribute__((ext_vector_type(4))) float f32x4;
typedef __attribute__((ext_vector_type(4))) float float4v;
typedef __attribute__((ext_vector_type(2))) float f32x2;

#define DMODEL 1024
#define DI 2048
#define NST 16
#define RANK 64
#define BB 2
#define LL 2048
#define MM (BB*LL)
#define LC 32
#define NCH (LL/LC)

__device__ __forceinline__ float b2f(u16 v){ union{unsigned u; float f;}x; x.u=(unsigned)v<<16; return x.f; }
__device__ __forceinline__ u16 f2b(float f){
  union{unsigned u; float f;}x; x.f=f;
  unsigned r = x.u + 0x7FFFu + ((x.u>>16)&1u);   // RNE
  return (u16)(r>>16);
}
// dtype probe on A_log: A_log[0]=log(1)=0.0f. f32 buffer -> u16[1]==0 (R5-validated: f32).
__device__ __forceinline__ bool probe_bf(const u16* probe){ return probe[1] != 0; }
__device__ __forceinline__ float ldin(const void* p, size_t i, bool bf){
  return bf ? b2f(((const u16*)p)[i]) : ((const float*)p)[i];
}
__device__ __forceinline__ u16 ldb(const void* p, size_t i, bool bf){
  return bf ? ((const u16*)p)[i] : f2b(((const float*)p)[i]);
}
// async global->LDS, 16B/lane; lds base MUST be wave-uniform (HW scatters lane*16)
__device__ __forceinline__ void gl16(const u16* g, char* lds_wave_base){
  __builtin_amdgcn_global_load_lds((const __attribute__((address_space(1))) unsigned*)g,
                                   (__attribute__((address_space(3))) unsigned*)lds_wave_base, 16, 0, 0);
}

// ============ 256x256 MFMA GEMM -- m201-style 8-phase schedule (T2+T3+T4+T5) ============
// (R7-verified: 43.9us GEMM1, MfmaUtil 30.7%, 0 conflicts.)  GEMM1 only.
// BK=64, 512 thr = 8 waves. STRIPE layout: wave (wr,wc) owns rows {wr*16+s*32, s=0..7},
// cols {wc*16+s2*64, s2=0..3} -> each LDS half-tile (A0/A1/B0/B1, 16KB) is read entirely
// in ONE phase: P1=(A0,B0):12 ds_read, P2=(B1):4, P3=(A1):8, P4: 0.  One half-tile
// stage (2 gl16) per phase into a provably-idle region:
//   P1->A1(kt+1), P2->B1(kt+1), P3->A0(kt+2), P4->B0(kt+2).
// vmcnt(4) ONCE per K-tile at P4 -- never 0 mid-loop.  Per phase: reads; stage;
// barrier; lgkmcnt(0); sched_barrier (rule 18); setprio(1); 16 MFMA; setprio(0); barrier.
// Swizzle (rule 21, both sides): 16B-chunk ^= row&7 (0-conflict at 128B rows).
// EPI: 1 = f32 partial store; 4 = bf16 x/z split via LDS-staged coalesced stores.
template<int EPI>
__global__ __launch_bounds__(512,2) void mgemm256_k(
    const u16* __restrict__ A, const u16* __restrict__ Bt,
    void* __restrict__ O0, void* __restrict__ O1,
    int M, int N, int K, int lda, int ldb, int ldc)
{
  __shared__ char smem[131072];
  const int t = threadIdx.x;
  int bx = blockIdx.x, by = blockIdx.y;
  { // XCD swizzle (bijective since gridX*gridY % 8 == 0)
    const int gx = gridDim.x;
    const int nwg = gx*gridDim.y;
    const int lin = by*gx + bx;
    const int swz = (lin & 7)*(nwg>>3) + (lin>>3);
    bx = swz % gx; by = swz / gx;
  }
  const int m0 = by*256, n0 = bx*256;
  const int kbeg = blockIdx.z * K;
  const int wv = t >> 6, ln = t & 63;
  const int wr = wv >> 2, wc = wv & 3;
  const int lr = ln & 15, q = ln >> 4;
  const int NT = K >> 6;

  // ---- staging geometry: one half-tile = 128 rows x 64k = 16KB = 2 gl16/thread
  const int srow8 = ln >> 3;                       // 0..7
  const int koff = ((ln & 7) ^ srow8) * 8;         // pre-XOR'd source chunk (u16 off)
  auto stA = [&](int kt, int h){
    char* d = smem + (kt&1)*65536 + h*16384;
    const u16* g = A + (size_t)(m0 + h*128 + wv*8 + srow8)*lda + kbeg + kt*64 + koff;
    gl16(g, d + wv*1024);
    gl16(g + (size_t)64*lda, d + 8192 + wv*1024);
  };
  auto stB = [&](int kt, int h){
    char* d = smem + (kt&1)*65536 + 32768 + h*16384;
    const u16* g = Bt + (size_t)(n0 + h*128 + wv*8 + srow8)*ldb + kbeg + kt*64 + koff;
    gl16(g, d + wv*1024);
    gl16(g + (size_t)64*ldb, d + 8192 + wv*1024);
  };

  // ---- ds_read offsets: stripe s rows wr*16+s*32 (half s>>2); stripe s2 cols wc*16+s2*64
  int arow[8], brow[4], ck[2];
#pragma unroll
  for(int s=0;s<8;s++)  arow[s] = (s>>2)*16384 + (wr*16 + (s&3)*32 + lr)*128;
#pragma unroll
  for(int s2=0;s2<4;s2++) brow[s2] = 32768 + (s2>>1)*16384 + (wc*16 + (s2&1)*64 + lr)*128;
#pragma unroll
  for(int ks=0;ks<2;ks++) ck[ks] = ((ks*4 + q) ^ (lr & 7)) * 16;

  f32x4 acc[8][4];
#pragma unroll
  for(int i=0;i<8;i++)
#pragma unroll
    for(int j=0;j<4;j++) acc[i][j] = (f32x4){0.f,0.f,0.f,0.f};

  // ---- prologue: tile0 complete + A0,B0 of tile1 in flight (steady-state entry)
  stA(0,0); stB(0,0); stA(0,1); stB(0,1);
  stA(1,0); stB(1,0);
  asm volatile("s_waitcnt vmcnt(4)" ::: "memory");
  __builtin_amdgcn_sched_barrier(0);
  __builtin_amdgcn_s_barrier();
  __builtin_amdgcn_sched_barrier(0);

  short8 aR[4][2], b0R[2][2], b1R[2][2];
  for(int kt=0; kt<NT; ++kt){
    const char* base = smem + (kt&1)*65536;
    // ======== P1: reads A0 stripes + B0 stripes; stage A1(kt+1) ========
#pragma unroll
    for(int s=0;s<4;s++)
#pragma unroll
      for(int ks=0;ks<2;ks++) aR[s][ks] = *(const short8*)(base + arow[s] + ck[ks]);
#pragma unroll
    for(int j=0;j<2;j++)
#pragma unroll
      for(int ks=0;ks<2;ks++) b0R[j][ks] = *(const short8*)(base + brow[j] + ck[ks]);
    if(kt+1 < NT) stA(kt+1, 1);
    __builtin_amdgcn_s_barrier();
    asm volatile("s_waitcnt lgkmcnt(0)" ::: "memory");
    __builtin_amdgcn_sched_barrier(0);
    __builtin_amdgcn_s_setprio(1);
#pragma unroll
    for(int s=0;s<4;s++)
#pragma unroll
      for(int j=0;j<2;j++)
#pragma unroll
        for(int ks=0;ks<2;ks++)
          acc[s][j] = __builtin_amdgcn_mfma_f32_16x16x32_bf16(aR[s][ks], b0R[j][ks], acc[s][j], 0,0,0);
    __builtin_amdgcn_s_setprio(0);
    __builtin_amdgcn_s_barrier();
    __builtin_amdgcn_sched_barrier(0);
    // ======== P2: reads B1 stripes; stage B1(kt+1) ========
#pragma unroll
    for(int j=0;j<2;j++)
#pragma unroll
      for(int ks=0;ks<2;ks++) b1R[j][ks] = *(const short8*)(base + brow[2+j] + ck[ks]);
    if(kt+1 < NT) stB(kt+1, 1);
    __builtin_amdgcn_s_barrier();
    asm volatile("s_waitcnt lgkmcnt(0)" ::: "memory");
    __builtin_amdgcn_sched_barrier(0);
    __builtin_amdgcn_s_setprio(1);
#pragma unroll
    for(int s=0;s<4;s++)
#pragma unroll
      for(int j=0;j<2;j++)
#pragma unroll
        for(int ks=0;ks<2;ks++)
          acc[s][2+j] = __builtin_amdgcn_mfma_f32_16x16x32_bf16(aR[s][ks], b1R[j][ks], acc[s][2+j], 0,0,0);
    __builtin_amdgcn_s_setprio(0);
    __builtin_amdgcn_s_barrier();
    __builtin_amdgcn_sched_barrier(0);
    // ======== P3: reads A1 stripes; stage A0(kt+2) ========
#pragma unroll
    for(int s=0;s<4;s++)
#pragma unroll
      for(int ks=0;ks<2;ks++) aR[s][ks] = *(const short8*)(base + arow[4+s] + ck[ks]);
    if(kt+2 < NT) stA(kt+2, 0);
    __builtin_amdgcn_s_barrier();
    asm volatile("s_waitcnt lgkmcnt(0)" ::: "memory");
    __builtin_amdgcn_sched_barrier(0);
    __builtin_amdgcn_s_setprio(1);
#pragma unroll
    for(int s=0;s<4;s++)
#pragma unroll
      for(int j=0;j<2;j++)
#pragma unroll
        for(int ks=0;ks<2;ks++)
          acc[4+s][j] = __builtin_amdgcn_mfma_f32_16x16x32_bf16(aR[s][ks], b0R[j][ks], acc[4+s][j], 0,0,0);
    __builtin_amdgcn_s_setprio(0);
    __builtin_amdgcn_s_barrier();
    __builtin_amdgcn_sched_barrier(0);
    // ======== P4: no reads; stage B0(kt+2); per-tile counted vmcnt ========
    if(kt+2 < NT){
      stB(kt+2, 0);
      asm volatile("s_waitcnt vmcnt(4)" ::: "memory");   // tile kt+1 fully landed
    } else if(kt+1 < NT){
      asm volatile("s_waitcnt vmcnt(0)" ::: "memory");   // drain for final tile
    }
    __builtin_amdgcn_sched_barrier(0);
    __builtin_amdgcn_s_barrier();
    __builtin_amdgcn_sched_barrier(0);
    __builtin_amdgcn_s_setprio(1);
#pragma unroll
    for(int s=0;s<4;s++)
#pragma unroll
      for(int j=0;j<2;j++)
#pragma unroll
        for(int ks=0;ks<2;ks++)
          acc[4+s][2+j] = __builtin_amdgcn_mfma_f32_16x16x32_bf16(aR[s][ks], b1R[j][ks], acc[4+s][2+j], 0,0,0);
    __builtin_amdgcn_s_setprio(0);
    __builtin_amdgcn_s_barrier();
    __builtin_amdgcn_sched_barrier(0);
  }

  // C/D per 16x16 frag (s,s2): row = m0 + wr*16 + s*32 + q*4 + r; col = n0 + wc*16 + s2*64 + lr
  if(EPI==4){
    u16* tile = (u16*)smem;                // [128][264] u16, reused LDS
    u16* obase = (n0 < DI) ? (u16*)O0 : (u16*)O1;
    const int cb = n0 & (DI-1);
    for(int h=0;h<2;h++){                  // h=0: frags s=0..3 (rows 0..127); h=1: s=4..7
      __builtin_amdgcn_s_barrier();
#pragma unroll
      for(int s=0;s<4;s++)
#pragma unroll
        for(int r=0;r<4;r++){
          int trow = wr*16 + s*32 + q*4 + r;       // 0..127 within half
#pragma unroll
          for(int s2=0;s2<4;s2++)
            tile[trow*264 + wc*16 + s2*64 + lr] = f2b(acc[h*4+s][s2][r]);
        }
      asm volatile("s_waitcnt lgkmcnt(0)" ::: "memory");
      __builtin_amdgcn_sched_barrier(0);
      __builtin_amdgcn_s_barrier();
      __builtin_amdgcn_sched_barrier(0);
#pragma unroll
      for(int it=0;it<8;it++){
        int idx = it*512 + t;              // 0..4095
        int row = idx >> 5;                // 0..127
        int ch  = (idx & 31) * 8;          // 0..248
        short8 v = *(const short8*)(tile + row*264 + ch);
        *(short8*)(obase + (size_t)(m0 + h*128 + row)*ldc + cb + ch) = v;
      }
    }
    return;
  }
  // EPI==1: direct f32 partial stores (16-lane contiguous 64B segments)
#pragma unroll
  for(int s=0;s<8;s++){
#pragma unroll
    for(int r=0;r<4;r++){
      int row = m0 + wr*16 + s*32 + q*4 + r;
#pragma unroll
      for(int s2=0;s2<4;s2++){
        int col = n0 + wc*16 + s2*64 + lr;
        ((float*)O0)[(size_t)blockIdx.z*M*ldc + (size_t)row*ldc + col] = acc[s][s2][r];
      }
    }
  }
}

// ---------------- MFMA GEMM 128x128 (m97 structure) -- GEMM3 + GEMM7, both split-K EPI1 --
// R8 lesson: this structure REQUIRES >=2 blocks/CU (grid >=512) -- at 1 block/CU the
// per-K-step vmcnt(0) drain is fully exposed (47us, MfmaUtil 12%). Keep split-K.
template<int EPI>
__global__ __launch_bounds__(256,2) void mgemm_k(
    const u16* __restrict__ A, const u16* __restrict__ Bt,
    void* __restrict__ O0, void* __restrict__ O1,
    const void* __restrict__ bias, const u16* __restrict__ probe,
    int M, int N, int K, int lda, int ldb, int ldc)
{
  __shared__ char smem[16384];
  const int t = threadIdx.x;
  int bx = blockIdx.x, by = blockIdx.y;
  { // XCD swizzle (bijective since nwg%8==0)
    const int gx = gridDim.x;
    const int nwg = gx*gridDim.y;
    const int lin = by*gx + bx;
    const int swz = (lin & 7)*(nwg>>3) + (lin>>3);
    bx = swz % gx; by = swz / gx;
  }
  const int m0 = by*128, n0 = bx*128;
  const int kbeg = blockIdx.z * K;
  const int lane = t & 63;
  const int wv = t >> 6;
  const int wm = (wv>>1)*64, wn = (wv&1)*64;
  const int lr = lane & 15, q = lane >> 4;

  const int r0 = t>>2, q0 = t&3;
  const u16* Ag0 = A + kbeg + (size_t)(m0 + r0)*lda + q0*8;
  const u16* Ag1 = A + kbeg + (size_t)(m0 + 64 + r0)*lda + q0*8;
  const u16* Bg0 = Bt + kbeg + (size_t)(n0 + r0)*ldb + q0*8;
  const u16* Bg1 = Bt + kbeg + (size_t)(n0 + 64 + r0)*ldb + q0*8;
  char* const wbase = smem + (t & ~63)*16;
  char* const lA0 = wbase;
  char* const lA1 = wbase + 4096;
  char* const lB0 = wbase + 8192;
  char* const lB1 = wbase + 12288;

  int aro[4], bro[4];
#pragma unroll
  for(int i=0;i<4;i++) aro[i] = (wm + i*16 + lr)*64 + q*16;
#pragma unroll
  for(int j=0;j<4;j++) bro[j] = (wn + j*16 + lr)*64 + q*16;

  f32x4 acc[4][4];
#pragma unroll
  for(int i=0;i<4;i++)
#pragma unroll
    for(int j=0;j<4;j++) acc[i][j] = (f32x4){0.f,0.f,0.f,0.f};

  for(int k0=0;k0<K;k0+=32){
    __syncthreads();
    gl16(Ag0 + k0, lA0); gl16(Ag1 + k0, lA1);
    gl16(Bg0 + k0, lB0); gl16(Bg1 + k0, lB1);
    __syncthreads();
    short8 af[4], bfv[4];
#pragma unroll
    for(int i=0;i<4;i++) af[i] = *(const short8*)(smem + aro[i]);
#pragma unroll
    for(int j=0;j<4;j++) bfv[j] = *(const short8*)(smem + 8192 + bro[j]);
#pragma unroll
    for(int i=0;i<4;i++)
#pragma unroll
      for(int j=0;j<4;j++)
        acc[i][j] = __builtin_amdgcn_mfma_f32_16x16x32_bf16(af[i], bfv[j], acc[i][j], 0,0,0);
  }

#pragma unroll
  for(int i=0;i<4;i++){
#pragma unroll
    for(int r=0;r<4;r++){
      int row = m0 + wm + i*16 + q*4 + r;
#pragma unroll
      for(int j=0;j<4;j++){
        int col = n0 + wn + j*16 + lr;
        ((float*)O0)[(size_t)blockIdx.z*M*ldc + (size_t)row*ldc + col] = acc[i][j][r];
      }
    }
  }
}

// ---------------- split-K(2) reduce for out: flagged store ----------------
__global__ __launch_bounds__(256) void red7_k(
    const float* __restrict__ P, void* __restrict__ out, const u16* __restrict__ probe)
{
  const bool bf = probe_bf(probe);
  size_t i = ((size_t)blockIdx.x*256 + threadIdx.x)*4;   // over M*DMODEL
  float4v a = *(const float4v*)(P + i);
  float4v b = *(const float4v*)(P + (size_t)MM*DMODEL + i);
  float4v s = a + b;
  if(bf){
    short4v r; r[0]=(short)f2b(s[0]); r[1]=(short)f2b(s[1]); r[2]=(short)f2b(s[2]); r[3]=(short)f2b(s[3]);
    *(short4v*)((u16*)out + i) = r;
  } else {
    *(float4v*)((float*)out + i) = s;
  }
}

// ---------------- dt_k: delta = softplus(xdblb[:,:64] @ WdtT^T + b_dt) -> bf16 ----------------
// K=64 in ONE LDS shot: A 16KB + B 16KB, 8 gl16/thread, one barrier, 32 MFMA,
// branchless softplus, LDS-staged coalesced stores. (R5: fixed the 124us outlier.)
__global__ __launch_bounds__(256,2) void dt_k(
    const u16* __restrict__ A,      // xdblb [M][128], cols 0..63 used
    const u16* __restrict__ Bt,     // WdtT [2048][64]
    u16* __restrict__ O,            // dlb [M][2048]
    const void* __restrict__ bias, const u16* __restrict__ probe)
{
  const bool bf = probe_bf(probe);
  __shared__ char smem[33792];      // A @0 (16KB), B @16384 (16KB); epi reuses as [128][132] u16
  const int t = threadIdx.x;
  int bx = blockIdx.x, by = blockIdx.y;
  { // XCD swizzle (nwg = 512, %8==0)
    const int gx = gridDim.x;
    const int nwg = gx*gridDim.y;
    const int lin = by*gx + bx;
    const int swz = (lin & 7)*(nwg>>3) + (lin>>3);
    bx = swz % gx; by = swz / gx;
  }
  const int m0 = by*128, n0 = bx*128;
  const int lane = t & 63, wv = t >> 6;
  const int wm = (wv>>1)*64, wn = (wv&1)*64;
  const int lr = lane & 15, q = lane >> 4;

  // staging: 4 rounds x 32 rows; thread t -> row t>>3, 16B chunk t&7;
  // source k-chunk pre-XOR'd with row&7 (both-sides swizzle).
  const int srow = t >> 3;
  const int koff = (((t&7) ^ (srow&7)) * 8);       // u16 offset in 64-col row
  const u16* gA = A  + (size_t)(m0 + srow)*128 + koff;
  const u16* gB = Bt + (size_t)(n0 + srow)*64  + koff;
  char* const lA = smem + wv*1024;                 // wave-uniform; lane*16 covers 8 rows
  char* const lB = smem + 16384 + wv*1024;
#pragma unroll
  for(int r=0;r<4;r++){
    gl16(gA + (size_t)r*32*128, lA + r*4096);
    gl16(gB + (size_t)r*32*64,  lB + r*4096);
  }
  __syncthreads();                                 // full drain (vmcnt 0) + barrier

  f32x4 acc[4][4];
#pragma unroll
  for(int i=0;i<4;i++)
#pragma unroll
    for(int j=0;j<4;j++) acc[i][j] = (f32x4){0.f,0.f,0.f,0.f};

#pragma unroll
  for(int ks=0;ks<2;ks++){
    short8 af[4], bfv[4];
#pragma unroll
    for(int i=0;i<4;i++){
      int row = wm + i*16 + lr;
      af[i] = *(const short8*)(smem + row*128 + (((ks*4+q) ^ (row&7))*16));
    }
#pragma unroll
    for(int j=0;j<4;j++){
      int row = wn + j*16 + lr;
      bfv[j] = *(const short8*)(smem + 16384 + row*128 + (((ks*4+q) ^ (row&7))*16));
    }
#pragma unroll
    for(int i=0;i<4;i++)
#pragma unroll
      for(int j=0;j<4;j++)
        acc[i][j] = __builtin_amdgcn_mfma_f32_16x16x32_bf16(af[i], bfv[j], acc[i][j], 0,0,0);
  }

  // epilogue: bias + fast softplus -> LDS tile [128][132] -> coalesced short8 stores
  float bj[4];
#pragma unroll
  for(int j=0;j<4;j++) bj[j] = ldin(bias, n0 + wn + j*16 + lr, bf);
  __syncthreads();
  u16* tile = (u16*)smem;
#pragma unroll
  for(int i=0;i<4;i++)
#pragma unroll
    for(int r=0;r<4;r++){
      int trow = wm + i*16 + q*4 + r;
#pragma unroll
      for(int j=0;j<4;j++){
        int tcol = wn + j*16 + lr;
        float s = acc[i][j][r] + bj[j];
        float e = __expf(-fabsf(s));
        float sp = fmaxf(s, 0.f) + __logf(1.f + e);
        tile[trow*132 + tcol] = f2b(sp);
      }
    }
  __syncthreads();
#pragma unroll
  for(int it=0;it<8;it++){
    int idx = it*256 + t;            // 0..2047
    int row = idx >> 4;              // 0..127
    int colc = (idx & 15) * 8;       // 0..120
    short8 v = *(const short8*)(tile + row*132 + colc);
    *(short8*)(O + (size_t)(m0+row)*DI + n0 + colc) = v;
  }
}

// ---------------- prep: 4 weight transposes + hidden convert, one launch ----------------
__device__ __forceinline__ void tr_block(
    const void* src, u16* dst, int R, int C, int bx, int by, bool bf, bool perm,
    int tid, u16 (*tile)[33])
{
  const int c0 = bx*32, r0 = by*32;
  const int tc = tid & 31, tr0 = tid >> 5;
#pragma unroll
  for(int i=0;i<4;i++){
    int r = tr0 + i*8;
    int gc = c0 + tc;
    tile[r][tc] = (gc < C) ? ldb(src, (size_t)(r0+r)*C + gc, bf) : (u16)0;
  }
  __syncthreads();
#pragma unroll
  for(int i=0;i<4;i++){
    int dr = c0 + tr0 + i*8;
    if(perm) dr = (dr>>1) + ((dr&1)<<11);   // even cols -> rows 0..2047 (x), odd -> 2048..4095 (z)
    int dc = r0 + tc;
    dst[(size_t)dr*R + dc] = tile[tc][tr0 + i*8];
  }
}

__global__ __launch_bounds__(256) void prep_k(
    const void* __restrict__ W_in, const void* __restrict__ W_out,
    const void* __restrict__ W_x, const void* __restrict__ W_dt,
    const void* __restrict__ hidden,
    u16* __restrict__ WinT, u16* __restrict__ WoutT, u16* __restrict__ WxT,
    u16* __restrict__ WdtT, u16* __restrict__ hb, const u16* __restrict__ probe)
{
  const bool bf = probe_bf(probe);
  __shared__ u16 tile[32][33];
  const int bid = blockIdx.x, t = threadIdx.x;
  if(bid < 4096){                 // W_in [1024][4096] -> [4096][1024] permuted, grid 128x32
    tr_block(W_in, WinT, DMODEL, 2*DI, bid & 127, bid >> 7, bf, true, t, tile);
  } else if(bid < 6144){          // W_out [2048][1024] -> [1024][2048], grid 32x64
    int b2 = bid - 4096; tr_block(W_out, WoutT, DI, DMODEL, b2 & 31, b2 >> 5, bf, false, t, tile);
  } else if(bid < 6400){          // W_x [2048][96] -> [128][2048] pad, grid 4x64
    int b2 = bid - 6144; tr_block(W_x, WxT, DI, 96, b2 & 3, b2 >> 2, bf, false, t, tile);
  } else if(bid < 6528){          // W_dt [64][2048] -> [2048][64], grid 64x2
    int b2 = bid - 6400; tr_block(W_dt, WdtT, RANK, DI, b2 & 63, b2 >> 6, bf, false, t, tile);
  } else {                        // hidden convert -> bf16, 8 elems/thread
    size_t i = ((size_t)(bid - 6528)*256 + t)*8;
    if(bf){
      *(short8*)(hb+i) = *(const short8*)((const u16*)hidden + i);
    } else {
      float4v a = *(const float4v*)((const float*)hidden + i);
      float4v b = *(const float4v*)((const float*)hidden + i + 4);
      short8 r;
      r[0]=(short)f2b(a[0]); r[1]=(short)f2b(a[1]); r[2]=(short)f2b(a[2]); r[3]=(short)f2b(a[3]);
      r[4]=(short)f2b(b[0]); r[5]=(short)f2b(b[1]); r[6]=(short)f2b(b[2]); r[7]=(short)f2b(b[3]);
      *(short8*)(hb+i) = r;
    }
  }
}

// ---------------- split-K(8) reduce for xdbl: f32 + bf16 copies ----------------
__global__ __launch_bounds__(256) void redx_k(
    const float* __restrict__ P, float* __restrict__ xdbl, u16* __restrict__ xdblb)
{
  size_t i = ((size_t)blockIdx.x*256 + threadIdx.x)*4;   // over M*128
  float4v s = *(const float4v*)(P + i);
#pragma unroll
  for(int p=1;p<8;p++) s += *(const float4v*)(P + (size_t)p*MM*128 + i);
  *(float4v*)(xdbl + i) = s;
  short4v r; r[0]=(short)f2b(s[0]); r[1]=(short)f2b(s[1]); r[2]=(short)f2b(s[2]); r[3]=(short)f2b(s[3]);
  *(short4v*)(xdblb + i) = r;
}

// ---------------- depthwise conv (K=4, pad 1 left / 2 right) + bias + silu ----------------
__global__ __launch_bounds__(256) void conv_silu_k(
  const u16* __restrict__ xb, const void* __restrict__ w,
  const void* __restrict__ bias, u16* __restrict__ xcb,
  const u16* __restrict__ probe)
{
  const bool bf = probe_bf(probe);
  const int row = blockIdx.x;              // 0..MM-1
  const int tt = row & (LL-1);
  const int d = threadIdx.x*8;
  float wv[4][8], bv[8];
  if(bf){
    short8 bb = *(const short8*)((const u16*)bias + d);
#pragma unroll
    for(int j=0;j<8;j++) bv[j] = b2f((u16)bb[j]);
#pragma unroll
    for(int k=0;k<4;k++){
      short8 ww = *(const short8*)((const u16*)w + k*DI + d);
#pragma unroll
      for(int j=0;j<8;j++) wv[k][j] = b2f((u16)ww[j]);
    }
  } else {
    *(float4v*)(bv)   = *(const float4v*)((const float*)bias + d);
    *(float4v*)(bv+4) = *(const float4v*)((const float*)bias + d + 4);
#pragma unroll
    for(int k=0;k<4;k++){
      *(float4v*)(wv[k])   = *(const float4v*)((const float*)w + k*DI + d);
      *(float4v*)(wv[k]+4) = *(const float4v*)((const float*)w + k*DI + d + 4);
    }
  }
  float acc[8];
#pragma unroll
  for(int j=0;j<8;j++) acc[j] = bv[j];
  const u16* xrow = xb + (size_t)row*DI + d;
#pragma unroll
  for(int k=0;k<4;k++){
    int o = tt - 1 + k;
    if(0<=o && o<LL){
      short8 xv = *(const short8*)(xrow + (ptrdiff_t)(k-1)*DI);
#pragma unroll
      for(int j=0;j<8;j++) acc[j] = fmaf(b2f((u16)xv[j]), wv[k][j], acc[j]);
    }
  }
  short8 sb;
#pragma unroll
  for(int j=0;j<8;j++){ float s = acc[j] / (1.f + __expf(-acc[j])); sb[j]=(short)f2b(s); }
  *(short8*)(xcb + (size_t)row*DI + d) = sb;
}

// ---------------- chunked selective scan (1 channel/thread, LC=32) ----------------
// 1024 blocks = 4 waves/SIMD; inner loop unroll x2, prefetch depth 2.
__global__ __launch_bounds__(256,4) void scan_a_k(
  const u16* __restrict__ dlb, const u16* __restrict__ xcb,
  const float* __restrict__ xdbl, const void* __restrict__ A_log,
  float* __restrict__ Bacc, float* __restrict__ sumdv,
  const u16* __restrict__ probe)
{
  const bool bf = probe_bf(probe);
  __shared__ float Bsh[LC][NST];
  const int t = threadIdx.x;
  const int d0 = blockIdx.x*256 + t;
  const int b = blockIdx.y, c = blockIdx.z;
  for(int i=t;i<LC*NST;i+=256){
    int l = i>>4, n = i&15;
    Bsh[l][n] = xdbl[((size_t)b*LL + (size_t)c*LC + l)*128 + 64 + n];
  }
  __syncthreads();
  float ac[NST], s[NST];
#pragma unroll
  for(int n=0;n<NST;n++){
    ac[n] = -__expf(ldin(A_log, (size_t)d0*NST+n, bf));
    s[n]=0.f;
  }
  bool geom = true;
  {
    float a0 = ac[0];
#pragma unroll
    for(int n=1;n<NST;n++) geom = geom && (fabsf(ac[n]-(n+1)*a0) <= 1e-4f*(n+1)*fabsf(a0));
  }
  float sum=0.f;
  const size_t base0 = ((size_t)b*LL + (size_t)c*LC)*DI + d0;
  const u16* dptr = dlb + base0;
  const u16* xptr = xcb + base0;

  auto stepA = [&](int l, u16 dp, u16 xp){
    float dv=b2f(dp), xv=b2f(xp);
    float du=dv*xv;
    sum+=dv;
    if(geom){
      float e=__expf(ac[0]*dv);
      float p=1.f;
#pragma unroll
      for(int n=0;n<NST;n++){
        p*=e; s[n]=fmaf(p, s[n], du*Bsh[l][n]);
      }
    } else {
#pragma unroll
      for(int n=0;n<NST;n++)
        s[n]=fmaf(__expf(ac[n]*dv), s[n], du*Bsh[l][n]);
    }
  };

  u16 dpA = dptr[0], xpA = xptr[0];
  u16 dpB = dptr[DI], xpB = xptr[DI];
  for(int l=0;l<LC;l+=2){
    int l2 = (l+2 < LC) ? l+2 : LC-1;   // tail: harmless duplicate load
    int l3 = (l+3 < LC) ? l+3 : LC-1;
    u16 dpC = dptr[(size_t)l2*DI], xpC = xptr[(size_t)l2*DI];
    u16 dpD = dptr[(size_t)l3*DI], xpD = xptr[(size_t)l3*DI];
    stepA(l,   dpA, xpA);
    stepA(l+1, dpB, xpB);
    dpA=dpC; xpA=xpC; dpB=dpD; xpB=xpD;
  }

  const size_t ob = ((size_t)c*BB + b)*((size_t)NST*DI) + d0;
#pragma unroll
  for(int n=0;n<NST;n++) Bacc[ob + (size_t)n*DI] = s[n];
  sumdv[((size_t)c*BB + b)*DI + d0] = sum;
}

// Phase B: prefix over chunks; a-coef recomputed from sumdv (exact algebra).
__global__ __launch_bounds__(256) void scan_b_k(
  const float* __restrict__ Bacc, const float* __restrict__ sumdv,
  const void* __restrict__ A_log, float* __restrict__ Sin,
  const u16* __restrict__ probe)
{
  const bool bf = probe_bf(probe);
  const int idx = blockIdx.x*256 + threadIdx.x;   // b*(NST*DI)+n*DI+d
  const int d = idx & (DI-1);
  const int n = (idx >> 11) & 15;
  const int b = idx >> 15;
  const float ac = -__expf(ldin(A_log, (size_t)d*NST+n, bf));
  float s = 0.f;
  float svN = sumdv[((size_t)0*BB + b)*DI + d];
  float bbN = Bacc[idx];
  for(int c=0;c<NCH;c++){
    int c1 = (c+1 < NCH) ? c+1 : NCH-1;
    float svC = sumdv[((size_t)c1*BB + b)*DI + d];
    float bbC = Bacc[(size_t)c1*((size_t)BB*NST*DI) + idx];
    float a = __expf(ac * svN);
    Sin[(size_t)c*((size_t)BB*NST*DI) + idx] = s;
    s = fmaf(a, s, bbN);
    svN = svC; bbN = bbC;
  }
}

// Phase C fused with gate (1 channel/thread): G = (y + xc*D)*silu(z), bf16 out
__global__ __launch_bounds__(256,4) void scan_c_gate_k(
  const u16* __restrict__ dlb, const u16* __restrict__ xcb,
  const float* __restrict__ xdbl, const void* __restrict__ A_log,
  const float* __restrict__ Sin, const u16* __restrict__ zb,
  const void* __restrict__ Dw, u16* __restrict__ G,
  const u16* __restrict__ probe)
{
  const bool bf = probe_bf(probe);
  __shared__ float Bsh[LC][NST], Csh[LC][NST];
  const int t = threadIdx.x;
  const int d0 = blockIdx.x*256 + t;
  const int b = blockIdx.y, c = blockIdx.z;
  for(int i=t;i<LC*NST;i+=256){
    int l = i>>4, n = i&15;
    size_t ro = ((size_t)b*LL + (size_t)c*LC + l)*128;
    Bsh[l][n] = xdbl[ro + 64 + n];
    Csh[l][n] = xdbl[ro + 80 + n];
  }
  __syncthreads();
  float ac[NST], s[NST];
  const size_t ib = ((size_t)c*BB + b)*((size_t)NST*DI) + d0;
#pragma unroll
  for(int n=0;n<NST;n++)
    ac[n] = -__expf(ldin(A_log, (size_t)d0*NST+n, bf));
#pragma unroll
  for(int n=0;n<NST;n++) s[n] = Sin[ib + (size_t)n*DI];
  bool geom = true;
  {
    float a0 = ac[0];
#pragma unroll
    for(int n=1;n<NST;n++) geom = geom && (fabsf(ac[n]-(n+1)*a0) <= 1e-4f*(n+1)*fabsf(a0));
  }
  const float D0 = ldin(Dw, d0, bf);
  const size_t base0 = ((size_t)b*LL + (size_t)c*LC)*DI + d0;
  const u16* dptr = dlb + base0;
  const u16* xptr = xcb + base0;
  const u16* zptr = zb  + base0;

  auto stepC = [&](int l, u16 dp, u16 xp, u16 zz){
    float dv=b2f(dp), xv=b2f(xp);
    float du=dv*xv;
    float y=0.f;
    if(geom){
      float e=__expf(ac[0]*dv);
      float p=1.f;
#pragma unroll
      for(int n=0;n<NST;n++){
        p*=e; s[n]=fmaf(p, s[n], du*Bsh[l][n]); y=fmaf(s[n], Csh[l][n], y);
      }
    } else {
#pragma unroll
      for(int n=0;n<NST;n++){
        s[n]=fmaf(__expf(ac[n]*dv), s[n], du*Bsh[l][n]); y=fmaf(s[n], Csh[l][n], y);
      }
    }
    float z0 = b2f(zz);
    float g0 = z0 / (1.f + __expf(-z0));
    float o0 = (y + xv*D0) * g0;
    G[base0 + (size_t)l*DI] = f2b(o0);
  };

  u16 dpA = dptr[0], xpA = xptr[0], zzA = zptr[0];
  u16 dpB = dptr[DI], xpB = xptr[DI], zzB = zptr[DI];
  for(int l=0;l<LC;l+=2){
    int l2 = (l+2 < LC) ? l+2 : LC-1;
    int l3 = (l+3 < LC) ? l+3 : LC-1;
    u16 dpC = dptr[(size_t)l2*DI], xpC = xptr[(size_t)l2*DI], zzC = zptr[(size_t)l2*DI];
    u16 dpD = dptr[(size_t)l3*DI], xpD = xptr[(size_t)l3*DI], zzD = zptr[(size_t)l3*DI];
    stepC(l,   dpA, xpA, zzA);
    stepC(l+1, dpB, xpB, zzB);
    dpA=dpC; xpA=xpC; zzA=zzC; dpB=dpD; xpB=xpD; zzB=zzD;
  }
}

extern "C" void kernel_launch(void* const* d_in, const int* in_sizes, int n_in,
                              void* d_out, int out_size, void* d_ws, size_t ws_size,
                              hipStream_t stream)
{
  const void* hidden = d_in[0];
  const void* W_in   = d_in[1];
  const void* convw  = d_in[2];
  const void* convb  = d_in[3];
  const void* W_x    = d_in[4];
  const void* W_dt   = d_in[5];
  const void* b_dt   = d_in[6];
  const u16*  A_log  = (const u16*)d_in[7];   // also the dtype probe
  const void* Dw     = d_in[8];
  const void* W_out  = d_in[9];

  char* p = (char*)d_ws;
  u16*   xb   = (u16*)  p;                       // 16.8 MB (GEMM1 -> conv); then:
  float* Sin  = (float*)p;                       //   alias 16.8 MB (scan_b -> scan_c)
  float* Pw7  = (float*)p;                       //   alias 33.5 MB GEMM7 partials x2 (Sin/xb/zb dead)
  u16*   zb   = (u16*)  (p + 16777216);          // 16.8 MB (GEMM1 -> scan_c)
  u16*   xcb  = (u16*)  (p + 33554432);          // 16.8 MB (conv -> GEMM3/scans)
  float* Bcc  = (float*)(p + 67108864);          // 16.8 MB (scan_a -> scan_b)
  u16*   G    = (u16*)  (p + 83886080);          // 16.8 MB (scan_c -> GEMM7)
  // 33.5 MB region at 100663296, sequential reuse:
  float* Pw   = (float*)(p + 100663296);         //   GEMM3 partials 8x2.1 MB (-> redx)
  u16*   dlb  = (u16*)  (p + 100663296);         //   delta bf16 16.8 MB (dt_k -> scans)
  u16*   hb   = (u16*)  (p + 117440512);         //   hidden bf16 8.4 MB (prep -> GEMM1)
  float* sumdv= (float*)(p + 117440512);         //   1 MB (scan_a -> scan_b; hb dead)
  float* xdbl = (float*)(p + 134217728);         // 2.1 MB  [M][128] f32
  u16*   xdblb= (u16*)  (p + 136314880);         // 1.05 MB [M][128] bf16
  u16*   WinT = (u16*)  (p + 137363456);         // 8.4 MB  [4096][1024] (row-permuted: x|z)
  u16*   WoutT= (u16*)  (p + 145752064);         // 4.2 MB  [1024][2048]
  u16*   WxT  = (u16*)  (p + 149946368);         // 0.5 MB  [128][2048] zero-padded
  u16*   WdtT = (u16*)  (p + 150470656);         // 0.25 MB [2048][64]

  // 0. one-shot prep: 4 transposes (W_in row-permuted) + hidden convert
  prep_k<<<6528 + (MM*DMODEL)/(256*8), 256, 0, stream>>>(
      W_in, W_out, W_x, W_dt, hidden, WinT, WoutT, WxT, WdtT, hb, A_log);
  // 1. xz = hidden @ W_in -> xb / zb, 256^2 8-phase pipelined GEMM
  mgemm256_k<4><<<dim3(16,16), 512, 0, stream>>>(hb, WinT, xb, zb,
                                                 MM, 2*DI, DMODEL, DMODEL, DMODEL, DI);
  // 2. xcb = silu(conv(xb)+bias)  (bf16 in/out, one block per row)
  conv_silu_k<<<MM, 256, 0, stream>>>(xb, convw, convb, xcb, A_log);
  // 3. xdbl = xc @ W_x  (N pad 128), split-K x8 -> partials -> reduce
  mgemm_k<1><<<dim3(1,32,8), 256, 0, stream>>>(xcb, WxT, Pw, nullptr, nullptr, A_log,
                                               MM, 128, DI/8, DI, DI, 128);
  redx_k<<<(MM*128)/(256*4), 256, 0, stream>>>(Pw, xdbl, xdblb);
  // 4. delta = softplus(xdbl[:, :64] @ W_dt + b_dt) -- dedicated single-shot kernel
  dt_k<<<dim3(16,32), 256, 0, stream>>>(xdblb, WdtT, dlb, b_dt, A_log);
  // 5. chunked selective scan (+ fused gate); 1 channel/thread, 1024 blocks
  scan_a_k<<<dim3(DI/256, BB, NCH), 256, 0, stream>>>(dlb, xcb, xdbl, A_log, Bcc, sumdv, A_log);
  scan_b_k<<<(BB*NST*DI)/256, 256, 0, stream>>>(Bcc, sumdv, A_log, Sin, A_log);
  scan_c_gate_k<<<dim3(DI/256, BB, NCH), 256, 0, stream>>>(dlb, xcb, xdbl, A_log, Sin, zb, Dw, G, A_log);
  // 6. out = G @ W_out -- split-K x2 (512 blocks = 2 blocks/CU; R8 showed 1 block/CU
  //    exposes the drain: 47us @ MfmaUtil 12%) -> partials at ws+0 -> flagged reduce
  mgemm_k<1><<<dim3(DMODEL/128, MM/128, 2), 256, 0, stream>>>(G, WoutT, Pw7, nullptr, nullptr, A_log,
                                                              MM, DMODEL, DI/2, DI, DI, DMODEL);
  red7_k<<<(MM*DMODEL)/(256*4), 256, 0, stream>>>(Pw7, d_out, A_log);
}